// Round 9
// baseline (80.070 us; speedup 1.0000x reference)
//
#include <hip/hip_runtime.h>
#include <hip/hip_cooperative_groups.h>

// DependencyGenerator, R9: single cooperative kernel.
//  Phase A: stage row entries to LDS (overlaps fill issue).
//  Phase B: global grid-stride fill — EXACT rocclr fillBuffer shape
//           (256 blocks x 256 thr, one tight global frontier, ~6.9 TB/s).
//  grid.sync() orders fill stores before scatter stores (replaces 2nd
//           dispatch; per-block-ownership fills measured ~2x slower).
//  Phase C: parity-split per-row scan (fixed-bound, pipelined LDS reads),
//           last-duplicate-wins, scattered stores.

#define SEQ_L   512
#define LM1     511                 // scatter entries per row
#define ROWELEM (SEQ_L * SEQ_L)     // 262144 floats per row
#define NT      256
#define BLOCKS  256                 // 2 blocks per row * 128 rows; 1/CU

typedef float vfloat4 __attribute__((ext_vector_type(4)));

__global__ __launch_bounds__(NT) void depmask_coop(
    const int*   __restrict__ dep_i,
    const int*   __restrict__ dep_j,
    const int*   __restrict__ dep_type,
    const float* __restrict__ dep_emb,
    float*       __restrict__ out,
    unsigned int n4)
{
    __shared__ int   s_idx[LM1];
    __shared__ float s_val[LM1];

    const int bid = blockIdx.x;
    const int row = bid >> 1;          // blocks 2r,2r+1 both handle row r
    const int par = bid & 1;           // parity split of the 511 entries
    const int t   = threadIdx.x;

    // Phase A: stage this row's entries (coalesced; 2x redundant, ~4KB).
    const int base = row * LM1;
    for (int k = t; k < LM1; k += NT) {
        s_idx[k] = dep_i[base + k] * SEQ_L + dep_j[base + k];
        s_val[k] = dep_emb[dep_type[base + k]];   // 53-entry table, L1
    }

    // Phase B: global grid-stride fill, rocclr pattern (proven 6.9 TB/s).
    {
        const vfloat4 ones = {1.f, 1.f, 1.f, 1.f};
        vfloat4* o4 = reinterpret_cast<vfloat4*>(out);
        const unsigned int stride = BLOCKS * NT;       // 65536 f4 = 1 MB
        unsigned int i = bid * NT + t;
        #pragma unroll 4
        for (; i < n4; i += stride)
            o4[i] = ones;
    }

    // Grid-wide barrier: all fill stores complete & visible before scatter.
    cooperative_groups::this_grid().sync();

    // Phase C: entry k = 2t+par; last duplicate wins via fixed-bound scan
    // (no break -> unrolled, pipelined ds_reads; ~510 reads ~= 1.3us).
    const int k = 2 * t + par;
    if (k < LM1) {
        const int idx = s_idx[k];
        bool last = true;
        for (int k2 = k + 1; k2 < LM1; ++k2)
            last &= (s_idx[k2] != idx);
        if (last) out[(size_t)row * ROWELEM + idx] = s_val[k];
    }
}

extern "C" void kernel_launch(void* const* d_in, const int* in_sizes, int n_in,
                              void* d_out, int out_size, void* d_ws, size_t ws_size,
                              hipStream_t stream) {
    const int*   dep_i    = (const int*)  d_in[0];
    const int*   dep_j    = (const int*)  d_in[1];
    const int*   dep_type = (const int*)  d_in[2];
    // d_in[3] = seq_len scalar (512) -- compile-time constant here
    const float* dep_emb  = (const float*)d_in[4];
    float*       out      = (float*)      d_out;

    const int b = in_sizes[0] / LM1;                      // 128
    unsigned int n4 = (unsigned int)((size_t)b * ROWELEM / 4);

    void* args[] = {(void*)&dep_i, (void*)&dep_j, (void*)&dep_type,
                    (void*)&dep_emb, (void*)&out, (void*)&n4};
    hipLaunchCooperativeKernel((void*)depmask_coop,
                               dim3(2 * b), dim3(NT), args, 0, stream);
}

// Round 10
// 30.326 us; speedup vs baseline: 2.6403x; 2.6403x over previous
//
#include <hip/hip_runtime.h>

// DependencyGenerator, R10: two-kernel split (R7 skeleton).
//  fill: unchanged from R7 (256 blocks x 256 thr grid-stride float4).
//  scatter: O(n) last-duplicate-wins via LDS open-addressing hash table
//           (atomicCAS slot claim + atomicMax on entry ordinal k),
//           replacing R7's O(n^2) variable-trip scan (~10us -> ~2us).
//           Entries live in registers; no s_idx/s_val arrays.

#define SEQ_L   512
#define LM1     511                 // scatter entries per row
#define ROWELEM (SEQ_L * SEQ_L)     // 262144 floats per row
#define NT      256
#define FILL_BLOCKS 256             // ~1 block per CU
#define HSLOTS  2048                // load factor 0.25 -> ~1.3 probes

typedef float vfloat4 __attribute__((ext_vector_type(4)));

__global__ __launch_bounds__(NT) void fill_kernel(float* __restrict__ out,
                                                  unsigned int n4)
{
    const vfloat4 ones = {1.f, 1.f, 1.f, 1.f};
    vfloat4* o4 = reinterpret_cast<vfloat4*>(out);
    const unsigned int stride = FILL_BLOCKS * NT;          // 65536 f4 = 1 MB
    unsigned int i = blockIdx.x * NT + threadIdx.x;
    #pragma unroll 4
    for (; i < n4; i += stride)
        o4[i] = ones;
}

__device__ __forceinline__ unsigned hash_idx(int idx) {
    return ((unsigned)idx * 2654435761u) >> 21;            // 11 bits
}

__global__ __launch_bounds__(NT) void scatter_kernel(
    const int*   __restrict__ dep_i,
    const int*   __restrict__ dep_j,
    const int*   __restrict__ dep_type,
    const float* __restrict__ dep_emb,
    float*       __restrict__ out)
{
    __shared__ int h_key[HSLOTS];
    __shared__ int h_max[HSLOTS];

    const int row = blockIdx.x;
    const int t   = threadIdx.x;

    for (int h = t; h < HSLOTS; h += NT) { h_key[h] = -1; h_max[h] = -1; }

    // Stage this thread's <=2 entries in REGISTERS.
    const int base = row * LM1;
    const int k0 = t, k1 = t + NT;                         // k0 < 511 always
    const int   idx0 = dep_i[base + k0] * SEQ_L + dep_j[base + k0];
    const float val0 = dep_emb[dep_type[base + k0]];
    int idx1 = -1; float val1 = 0.f;
    if (k1 < LM1) {
        idx1 = dep_i[base + k1] * SEQ_L + dep_j[base + k1];
        val1 = dep_emb[dep_type[base + k1]];
    }
    __syncthreads();                                       // table init done

    // Insert: claim a slot per distinct idx, record max ordinal k.
    {
        unsigned h = hash_idx(idx0);
        while (true) {
            int prev = atomicCAS(&h_key[h], -1, idx0);
            if (prev == -1 || prev == idx0) { atomicMax(&h_max[h], k0); break; }
            h = (h + 1) & (HSLOTS - 1);
        }
    }
    if (idx1 >= 0) {
        unsigned h = hash_idx(idx1);
        while (true) {
            int prev = atomicCAS(&h_key[h], -1, idx1);
            if (prev == -1 || prev == idx1) { atomicMax(&h_max[h], k1); break; }
            h = (h + 1) & (HSLOTS - 1);
        }
    }
    __syncthreads();                                       // table stable

    // Query: entry k is the last occurrence iff h_max[slot(idx)] == k.
    {
        unsigned h = hash_idx(idx0);
        while (h_key[h] != idx0) h = (h + 1) & (HSLOTS - 1);
        if (h_max[h] == k0) out[(size_t)row * ROWELEM + idx0] = val0;
    }
    if (idx1 >= 0) {
        unsigned h = hash_idx(idx1);
        while (h_key[h] != idx1) h = (h + 1) & (HSLOTS - 1);
        if (h_max[h] == k1) out[(size_t)row * ROWELEM + idx1] = val1;
    }
}

extern "C" void kernel_launch(void* const* d_in, const int* in_sizes, int n_in,
                              void* d_out, int out_size, void* d_ws, size_t ws_size,
                              hipStream_t stream) {
    const int*   dep_i    = (const int*)  d_in[0];
    const int*   dep_j    = (const int*)  d_in[1];
    const int*   dep_type = (const int*)  d_in[2];
    // d_in[3] = seq_len scalar (512) -- compile-time constant here
    const float* dep_emb  = (const float*)d_in[4];
    float*       out      = (float*)      d_out;

    const int b = in_sizes[0] / LM1;                       // 128
    const unsigned int n4 = (unsigned int)((size_t)b * ROWELEM / 4);

    fill_kernel<<<dim3(FILL_BLOCKS), dim3(NT), 0, stream>>>(out, n4);
    scatter_kernel<<<dim3(b), dim3(NT), 0, stream>>>(
        dep_i, dep_j, dep_type, dep_emb, out);
}